// Round 5
// baseline (324.757 us; speedup 1.0000x reference)
//
#include <hip/hip_runtime.h>

typedef __bf16 bf16x8 __attribute__((ext_vector_type(8)));
typedef float floatx4 __attribute__((ext_vector_type(4)));

#define B_   4
#define H_   16
#define S_   2048
#define D_   64
#define E_   1024
#define BS_  8192   // B_*S_

// 1/sqrt(64) * log2(e): folded into Q at projection time; attention uses exp2.
#define QSCALE 0.18033688011112042f

__device__ __forceinline__ floatx4 mfma16(bf16x8 a, bf16x8 b, floatx4 c) {
  return __builtin_amdgcn_mfma_f32_16x16x32_bf16(a, b, c, 0, 0, 0);
}

__device__ __forceinline__ unsigned short f2bf(float f) {
  union { float f; unsigned int u; } a;
  a.f = f;
  unsigned int u = a.u;
  return (unsigned short)((u + 0x7fffu + ((u >> 16) & 1u)) >> 16);
}

// pack two fp32 -> (bf16(a) | bf16(b)<<16), round-half-up, single v_perm each
__device__ __forceinline__ unsigned int pack2bf(float a, float b) {
  union { float f; unsigned int u; } ua, ub;
  ua.f = a; ub.f = b;
  return __builtin_amdgcn_perm(ub.u + 0x8000u, ua.u + 0x8000u, 0x07060302u);
}

// async global->LDS, 16B per lane. LDS dest = wave-uniform base + lane*16.
__device__ __forceinline__ void async16(const unsigned short* g, unsigned short* l) {
  __builtin_amdgcn_global_load_lds(
      (const __attribute__((address_space(1))) unsigned int*)g,
      (__attribute__((address_space(3))) unsigned int*)l, 16, 0, 0);
}

// ---------------------------------------------------------------------------
// Kernel 0: transpose-convert the four weight matrices W[k][n] (fp32) ->
// Wt[n][k] (bf16). grid (32,32,4), block (32,8).
// ---------------------------------------------------------------------------
__global__ __launch_bounds__(256) void transpose4(
    const float* __restrict__ W0, const float* __restrict__ W1,
    const float* __restrict__ W2, const float* __restrict__ W3,
    unsigned short* __restrict__ Wt) {
  __shared__ float tile[32][33];
  const float* src = blockIdx.z == 0 ? W0 : blockIdx.z == 1 ? W1
                   : blockIdx.z == 2 ? W2 : W3;
  unsigned short* dst = Wt + (size_t)blockIdx.z * E_ * E_;
  const int k0 = blockIdx.x * 32, n0 = blockIdx.y * 32;
  const int tx = threadIdx.x, ty = threadIdx.y;
#pragma unroll
  for (int i = 0; i < 32; i += 8)
    tile[ty + i][tx] = src[(size_t)(k0 + ty + i) * E_ + n0 + tx];
  __syncthreads();
#pragma unroll
  for (int i = 0; i < 32; i += 8)
    dst[(size_t)(n0 + ty + i) * E_ + k0 + tx] = f2bf(tile[tx][ty + i]);
}

// ---------------------------------------------------------------------------
// Kernel 0b: cast x fp32 -> bf16. grid 4096, block 256, 8 elems/thread.
// ---------------------------------------------------------------------------
__global__ __launch_bounds__(256) void cast_x(
    const float* __restrict__ x, unsigned short* __restrict__ xb) {
  const size_t i = ((size_t)blockIdx.x * 256 + threadIdx.x) * 8;
  const float4* p = (const float4*)(x + i);
  float4 a0 = p[0], a1 = p[1];
  union { unsigned short h[8]; uint4 u; } pk;
  pk.h[0] = f2bf(a0.x); pk.h[1] = f2bf(a0.y); pk.h[2] = f2bf(a0.z); pk.h[3] = f2bf(a0.w);
  pk.h[4] = f2bf(a1.x); pk.h[5] = f2bf(a1.y); pk.h[6] = f2bf(a1.z); pk.h[7] = f2bf(a1.w);
  *(uint4*)(xb + i) = pk.u;
}

// ---------------------------------------------------------------------------
// Shared GEMM guts: 128x128 tile, BK=32, 4 waves (2x2 of 64x64).
// 3-stage software pipeline: triple-buffered LDS (48 KB), ONE barrier per
// K-step. At iter k the barrier's vmcnt drain waits on DMAs issued at iter
// k-1 (a full iteration of latency already elapsed); then tile k+1's DMA is
// issued into buf (k+1)%3 (last read at iter k-2, protected by barrier k-1);
// then ds_read+MFMA on buf k%3. 16B-chunk XOR swizzle (phys = log ^
// ((r&3)^((r>>2)&1))) folded into the global source address keeps fragment
// ds_read_b128 conflict-free on the unpadded [128][32] tiles.
// ---------------------------------------------------------------------------
#define GEMM_CORE(APTR, BPTR)                                                  \
  __shared__ __align__(16) unsigned short As[3][128][32];                      \
  __shared__ __align__(16) unsigned short Bs[3][128][32];                      \
  const int t = threadIdx.x;                                                   \
  const int w = t >> 6, lane = t & 63, quad = lane >> 4, l15 = lane & 15;      \
  const int moff = (w >> 1) * 64, noff = (w & 1) * 64;                         \
  const int m0 = blockIdx.y * 128, n0 = blockIdx.x * 128;                      \
  const int r_loc = lane >> 2, cphys = lane & 3;                               \
  const int r0 = w * 32 + r_loc, r1 = r0 + 16;                                 \
  const int sw = (r0 & 3) ^ ((r0 >> 2) & 1); /* same for r1 (=r0+16) */        \
  const int clog = (cphys ^ sw) * 8;                                           \
  const unsigned short* gA0 = (APTR) + (size_t)(m0 + r0) * E_ + clog;          \
  const unsigned short* gA1 = (APTR) + (size_t)(m0 + r1) * E_ + clog;          \
  const unsigned short* gB0 = (BPTR) + (size_t)(n0 + r0) * E_ + clog;          \
  const unsigned short* gB1 = (BPTR) + (size_t)(n0 + r1) * E_ + clog;          \
  const int sF = (l15 & 3) ^ ((l15 >> 2) & 1); /* frag-read swizzle */         \
  const int fcol = ((quad ^ sF)) * 8;                                          \
  floatx4 acc[4][4] = {};                                                      \
  /* prologue: tile 0 -> buf 0 */                                              \
  async16(gA0, &As[0][w * 32][0]);                                             \
  async16(gA1, &As[0][w * 32 + 16][0]);                                        \
  async16(gB0, &Bs[0][w * 32][0]);                                             \
  async16(gB1, &Bs[0][w * 32 + 16][0]);                                        \
  int cb = 0;                                                                  \
  for (int it = 0; it < 32; ++it) {                                            \
    __syncthreads(); /* vmcnt drain covers DMAs issued at iter it-1 */         \
    const int nb = cb == 2 ? 0 : cb + 1;                                       \
    if (it + 1 < 32) {                                                         \
      const int kn = (it + 1) * 32;                                            \
      async16(gA0 + kn, &As[nb][w * 32][0]);                                   \
      async16(gA1 + kn, &As[nb][w * 32 + 16][0]);                              \
      async16(gB0 + kn, &Bs[nb][w * 32][0]);                                   \
      async16(gB1 + kn, &Bs[nb][w * 32 + 16][0]);                              \
    }                                                                          \
    bf16x8 af[4], bf[4];                                                       \
    _Pragma("unroll")                                                          \
    for (int i = 0; i < 4; i++)                                                \
      af[i] = *(const bf16x8*)&As[cb][moff + i * 16 + l15][fcol];              \
    _Pragma("unroll")                                                          \
    for (int j = 0; j < 4; j++)                                                \
      bf[j] = *(const bf16x8*)&Bs[cb][noff + j * 16 + l15][fcol];              \
    _Pragma("unroll")                                                          \
    for (int i = 0; i < 4; i++)                                                \
      _Pragma("unroll")                                                        \
      for (int j = 0; j < 4; j++) acc[i][j] = mfma16(af[i], bf[j], acc[i][j]); \
    cb = nb;                                                                   \
  }

// ---------------------------------------------------------------------------
// Kernel 1: QKV projection GEMM. grid (24, 64). Epilogue: bias, Q pre-scaled
// by QSCALE, Q/K -> [B,H,S,D] bf16, V -> [B,H,D,S'] bf16 (transposed AND
// key-permuted within each 64-block: s' = (s&~63) | ((s&15)*4 + ((s>>4)&3)).
// PV is invariant under a shared key permutation of P and V; this makes the
// attention P-writes b64-packable while keeping V staging/reads contiguous).
// ---------------------------------------------------------------------------
__global__ __launch_bounds__(256) void gemm_qkv(
    const unsigned short* __restrict__ xb, const unsigned short* __restrict__ Wt,
    const float* __restrict__ bq, const float* __restrict__ bk,
    const float* __restrict__ bv,
    unsigned short* __restrict__ Q, unsigned short* __restrict__ K,
    unsigned short* __restrict__ V) {
  GEMM_CORE(xb, Wt)

  const int which = n0 >> 10;
  const float* bias = which == 0 ? bq : (which == 1 ? bk : bv);
  unsigned short* dst = which == 0 ? Q : (which == 1 ? K : V);
  const float sc = which == 0 ? QSCALE : 1.0f;
#pragma unroll
  for (int j = 0; j < 4; j++) {
    const int n = (n0 + noff + j * 16 + l15) & 1023;
    const int h = n >> 6, d = n & 63;
    const float bb = bias[n];
#pragma unroll
    for (int i = 0; i < 4; i++) {
#pragma unroll
      for (int r = 0; r < 4; r++) {
        const int m = m0 + moff + i * 16 + quad * 4 + r;
        const int b = m >> 11, s = m & 2047;
        const float val = (acc[i][j][r] + bb) * sc;
        if (which == 2) {  // V transposed + key-permuted: [B,H,D,S']
          const int sp = (s & ~63) | (((s & 15) << 2) | ((s >> 4) & 3));
          dst[(((size_t)(b * H_ + h) * D_) + d) * S_ + sp] = f2bf(val);
        } else {
          dst[(((size_t)(b * H_ + h) * S_) + s) * D_ + d] = f2bf(val);
        }
      }
    }
  }
}

// ---------------------------------------------------------------------------
// Kernel 2: flash attention, no-max softmax, exp2 domain, scale in Q.
// grid (16, 64). 4 waves x 32 q-rows. 64-key tiles, register-pipelined K/V
// staging. P stored in LDS at key' = (key&15)*4 + (key>>4): one b64 write per
// 4 C-values, pairs packed with v_perm round-half-up. V arrives already
// key'-permuted, so all fragment reads stay b128. Output AO[b][s][h*64+d].
// ---------------------------------------------------------------------------
__global__ __launch_bounds__(256, 4) void attn_kernel(
    const unsigned short* __restrict__ Q, const unsigned short* __restrict__ K,
    const unsigned short* __restrict__ Vt, unsigned short* __restrict__ AO) {
  __shared__ __align__(16) unsigned short Ks[64][72];   // [key][d]
  __shared__ __align__(16) unsigned short Vs[64][72];   // [d][key']
  __shared__ __align__(16) unsigned short Ps[128][72];  // [q][key']
  const int t = threadIdx.x;
  const int w = t >> 6, lane = t & 63, quad = lane >> 4, l15 = lane & 15;
  const int bh = blockIdx.y;
  const int q0 = blockIdx.x * 128;
  const int qb = w * 32;
  const size_t base = (size_t)bh * S_ * D_;

  bf16x8 qf[2][2];
#pragma unroll
  for (int mt = 0; mt < 2; mt++)
#pragma unroll
    for (int ks = 0; ks < 2; ks++)
      qf[mt][ks] = *(const bf16x8*)(Q + base +
                    (size_t)(q0 + qb + mt * 16 + l15) * D_ + ks * 32 + quad * 8);

  float l_i[2][4] = {};
  floatx4 O[2][4] = {};

  const int kk = t >> 2, cc = (t & 3) * 16;
  const unsigned short* kp = K  + base + (size_t)kk * D_ + cc;
  const unsigned short* vp = Vt + base + (size_t)kk * S_ + cc;

  uint4 kr0 = *(const uint4*)(kp);
  uint4 kr1 = *(const uint4*)(kp + 8);
  uint4 vr0 = *(const uint4*)(vp);
  uint4 vr1 = *(const uint4*)(vp + 8);

  for (int kt0 = 0; kt0 < S_; kt0 += 64) {
    *(uint4*)&Ks[kk][cc]     = kr0;
    *(uint4*)&Ks[kk][cc + 8] = kr1;
    *(uint4*)&Vs[kk][cc]     = vr0;
    *(uint4*)&Vs[kk][cc + 8] = vr1;
    __syncthreads();

    if (kt0 + 64 < S_) {  // prefetch next tile into registers
      kr0 = *(const uint4*)(kp + (size_t)(kt0 + 64) * D_);
      kr1 = *(const uint4*)(kp + (size_t)(kt0 + 64) * D_ + 8);
      vr0 = *(const uint4*)(vp + kt0 + 64);
      vr1 = *(const uint4*)(vp + kt0 + 72);
    }

    // S = Q K^T  (C-tile kt covers keys kt*16 + l15)
    floatx4 s[2][4] = {};
#pragma unroll
    for (int kt = 0; kt < 4; kt++) {
#pragma unroll
      for (int ks = 0; ks < 2; ks++) {
        bf16x8 kf = *(const bf16x8*)&Ks[kt * 16 + l15][ks * 32 + quad * 8];
#pragma unroll
        for (int mt = 0; mt < 2; mt++) s[mt][kt] = mfma16(qf[mt][ks], kf, s[mt][kt]);
      }
    }

    // p = exp2(s); key kt*16+l15 -> LDS col key' = l15*4+kt: the 4 kt-values
    // per (mt,r) are contiguous -> single b64 write of 2 packed u32.
#pragma unroll
    for (int mt = 0; mt < 2; mt++) {
#pragma unroll
      for (int r = 0; r < 4; r++) {
        const float p0 = __builtin_amdgcn_exp2f(s[mt][0][r]);
        const float p1 = __builtin_amdgcn_exp2f(s[mt][1][r]);
        const float p2 = __builtin_amdgcn_exp2f(s[mt][2][r]);
        const float p3 = __builtin_amdgcn_exp2f(s[mt][3][r]);
        l_i[mt][r] += (p0 + p1) + (p2 + p3);
        uint2 pk;
        pk.x = pack2bf(p0, p1);
        pk.y = pack2bf(p2, p3);
        *(uint2*)((char*)&Ps[qb + mt * 16 + quad * 4 + r][0] + l15 * 8) = pk;
      }
    }

    // O += P V   (both operands in key' order; Ps rows wave-private)
#pragma unroll
    for (int ks = 0; ks < 2; ks++) {
      bf16x8 pf[2];
#pragma unroll
      for (int mt = 0; mt < 2; mt++)
        pf[mt] = *(const bf16x8*)&Ps[qb + mt * 16 + l15][ks * 32 + quad * 8];
#pragma unroll
      for (int dt = 0; dt < 4; dt++) {
        bf16x8 vf = *(const bf16x8*)&Vs[dt * 16 + l15][ks * 32 + quad * 8];
#pragma unroll
        for (int mt = 0; mt < 2; mt++) O[mt][dt] = mfma16(pf[mt], vf, O[mt][dt]);
      }
    }
    __syncthreads();
  }

  const int b = bh >> 4, h = bh & 15;
#pragma unroll
  for (int mt = 0; mt < 2; mt++)
#pragma unroll
    for (int r = 0; r < 4; r++) {
      float sum = l_i[mt][r];
#pragma unroll
      for (int off = 1; off < 16; off <<= 1) sum += __shfl_xor(sum, off, 64);
      const float inv = 1.f / sum;
      const int srow = q0 + qb + mt * 16 + quad * 4 + r;
      unsigned short* aop = AO + (size_t)(b * S_ + srow) * E_ + h * D_ + l15;
#pragma unroll
      for (int dt = 0; dt < 4; dt++)
        aop[dt * 16] = f2bf(O[mt][dt][r] * inv);
    }
}

// ---------------------------------------------------------------------------
// Kernel 3: output projection GEMM. grid (8, 64). fp32 out + bias.
// ---------------------------------------------------------------------------
__global__ __launch_bounds__(256) void gemm_out(
    const unsigned short* __restrict__ A, const unsigned short* __restrict__ Wt,
    const float* __restrict__ bo, float* __restrict__ Cout) {
  GEMM_CORE(A, Wt)

#pragma unroll
  for (int j = 0; j < 4; j++) {
    const int n = n0 + noff + j * 16 + l15;
    const float bb = bo[n];
#pragma unroll
    for (int i = 0; i < 4; i++) {
#pragma unroll
      for (int r = 0; r < 4; r++) {
        const int m = m0 + moff + i * 16 + quad * 4 + r;
        Cout[(size_t)m * E_ + n] = acc[i][j][r] + bb;
      }
    }
  }
}

// ---------------------------------------------------------------------------
extern "C" void kernel_launch(void* const* d_in, const int* in_sizes, int n_in,
                              void* d_out, int out_size, void* d_ws, size_t ws_size,
                              hipStream_t stream) {
  const float* x  = (const float*)d_in[0];
  const float* Wq = (const float*)d_in[1];
  const float* bq = (const float*)d_in[2];
  const float* Wk = (const float*)d_in[3];
  const float* bk = (const float*)d_in[4];
  const float* Wv = (const float*)d_in[5];
  const float* bv = (const float*)d_in[6];
  const float* Wo = (const float*)d_in[7];
  const float* bo = (const float*)d_in[8];
  float* out = (float*)d_out;

  unsigned short* Wt = (unsigned short*)d_ws;
  unsigned short* Qb = Wt + (size_t)4 * E_ * E_;
  unsigned short* Kb = Qb + (size_t)B_ * H_ * S_ * D_;
  unsigned short* Vb = Kb + (size_t)B_ * H_ * S_ * D_;
  unsigned short* xb = Vb + (size_t)B_ * H_ * S_ * D_;
  unsigned short* AO = xb;  // alias: xb dead after gemm_qkv

  transpose4<<<dim3(32, 32, 4), dim3(32, 8), 0, stream>>>(Wq, Wk, Wv, Wo, Wt);
  cast_x<<<dim3(BS_ * E_ / (256 * 8)), 256, 0, stream>>>(x, xb);
  gemm_qkv<<<dim3(24, 64), 256, 0, stream>>>(xb, Wt, bq, bk, bv, Qb, Kb, Vb);
  attn_kernel<<<dim3(16, 64), 256, 0, stream>>>(Qb, Kb, Vb, AO);
  gemm_out<<<dim3(8, 64), 256, 0, stream>>>(AO, Wt + (size_t)3 * E_ * E_, bo, out);
}

// Round 6
// 298.729 us; speedup vs baseline: 1.0871x; 1.0871x over previous
//
#include <hip/hip_runtime.h>

typedef __bf16 bf16x8 __attribute__((ext_vector_type(8)));
typedef float floatx4 __attribute__((ext_vector_type(4)));

#define B_   4
#define H_   16
#define S_   2048
#define D_   64
#define E_   1024
#define BS_  8192   // B_*S_

// 1/sqrt(64) * log2(e): folded into Q at projection time; attention uses exp2.
#define QSCALE 0.18033688011112042f

__device__ __forceinline__ floatx4 mfma16(bf16x8 a, bf16x8 b, floatx4 c) {
  return __builtin_amdgcn_mfma_f32_16x16x32_bf16(a, b, c, 0, 0, 0);
}

__device__ __forceinline__ unsigned short f2bf(float f) {
  union { float f; unsigned int u; } a;
  a.f = f;
  unsigned int u = a.u;
  return (unsigned short)((u + 0x7fffu + ((u >> 16) & 1u)) >> 16);
}

// pack two fp32 -> (bf16(a) | bf16(b)<<16), round-half-up, single v_perm each
__device__ __forceinline__ unsigned int pack2bf(float a, float b) {
  union { float f; unsigned int u; } ua, ub;
  ua.f = a; ub.f = b;
  return __builtin_amdgcn_perm(ub.u + 0x8000u, ua.u + 0x8000u, 0x07060302u);
}

// async global->LDS, 16B per lane. LDS dest = wave-uniform base + lane*16.
__device__ __forceinline__ void async16(const unsigned short* g, unsigned short* l) {
  __builtin_amdgcn_global_load_lds(
      (const __attribute__((address_space(1))) unsigned int*)g,
      (__attribute__((address_space(3))) unsigned int*)l, 16, 0, 0);
}

// ---------------------------------------------------------------------------
// Kernel 0: transpose-convert the four weight matrices W[k][n] (fp32) ->
// Wt[n][k] (bf16). grid (32,32,4), block (32,8).
// ---------------------------------------------------------------------------
__global__ __launch_bounds__(256) void transpose4(
    const float* __restrict__ W0, const float* __restrict__ W1,
    const float* __restrict__ W2, const float* __restrict__ W3,
    unsigned short* __restrict__ Wt) {
  __shared__ float tile[32][33];
  const float* src = blockIdx.z == 0 ? W0 : blockIdx.z == 1 ? W1
                   : blockIdx.z == 2 ? W2 : W3;
  unsigned short* dst = Wt + (size_t)blockIdx.z * E_ * E_;
  const int k0 = blockIdx.x * 32, n0 = blockIdx.y * 32;
  const int tx = threadIdx.x, ty = threadIdx.y;
#pragma unroll
  for (int i = 0; i < 32; i += 8)
    tile[ty + i][tx] = src[(size_t)(k0 + ty + i) * E_ + n0 + tx];
  __syncthreads();
#pragma unroll
  for (int i = 0; i < 32; i += 8)
    dst[(size_t)(n0 + ty + i) * E_ + k0 + tx] = f2bf(tile[tx][ty + i]);
}

// ---------------------------------------------------------------------------
// Kernel 0b: cast x fp32 -> bf16. grid 4096, block 256, 8 elems/thread.
// ---------------------------------------------------------------------------
__global__ __launch_bounds__(256) void cast_x(
    const float* __restrict__ x, unsigned short* __restrict__ xb) {
  const size_t i = ((size_t)blockIdx.x * 256 + threadIdx.x) * 8;
  const float4* p = (const float4*)(x + i);
  float4 a0 = p[0], a1 = p[1];
  union { unsigned short h[8]; uint4 u; } pk;
  pk.h[0] = f2bf(a0.x); pk.h[1] = f2bf(a0.y); pk.h[2] = f2bf(a0.z); pk.h[3] = f2bf(a0.w);
  pk.h[4] = f2bf(a1.x); pk.h[5] = f2bf(a1.y); pk.h[6] = f2bf(a1.z); pk.h[7] = f2bf(a1.w);
  *(uint4*)(xb + i) = pk.u;
}

// ---------------------------------------------------------------------------
// Shared GEMM guts: 128x128 tile, BK=32, 4 waves (2x2 of 64x64).
// Distance-2 pipeline, 3 DISTINCT LDS buffers, raw s_barrier with manual
// s_waitcnt vmcnt(4): at step k we wait only for the DMAs issued at step k-2
// (two full iterations of latency elapsed); the 4 newest DMAs (tile k+1)
// stay in flight across the barrier (AITER pattern: vmcnt never 0 until the
// tail). Distinct buffer objects + 3x-unrolled loop = compile-time LDS
// addresses (no spurious compiler drains, no per-iter address VALU).
// 16B-chunk XOR swizzle keeps fragment ds_read_b128 conflict-free on the
// unpadded [128][32] tiles.
// ---------------------------------------------------------------------------
#define GFRAG_MFMA(CA, CB)                                                     \
    bf16x8 af[4], bf[4];                                                       \
    _Pragma("unroll")                                                          \
    for (int i = 0; i < 4; i++)                                                \
      af[i] = *(const bf16x8*)&CA[moff + i * 16 + l15][fcol];                  \
    _Pragma("unroll")                                                          \
    for (int j = 0; j < 4; j++)                                                \
      bf[j] = *(const bf16x8*)&CB[noff + j * 16 + l15][fcol];                  \
    _Pragma("unroll")                                                          \
    for (int i = 0; i < 4; i++)                                                \
      _Pragma("unroll")                                                        \
      for (int j = 0; j < 4; j++) acc[i][j] = mfma16(af[i], bf[j], acc[i][j]);

#define GISSUE(NA, NB, KT)                                                     \
    { const int kn = (KT) * 32;                                                \
      async16(gA0 + kn, &NA[w * 32][0]);                                       \
      async16(gA1 + kn, &NA[w * 32 + 16][0]);                                  \
      async16(gB0 + kn, &NB[w * 32][0]);                                       \
      async16(gB1 + kn, &NB[w * 32 + 16][0]); }

#define GSTEP(CA, CB, NA, NB, KT)                                              \
    { __builtin_amdgcn_s_waitcnt(0x0F74); /* vmcnt(4): tile k-2 landed */      \
      __builtin_amdgcn_s_barrier();                                            \
      GISSUE(NA, NB, KT)                                                       \
      GFRAG_MFMA(CA, CB) }

#define GSTEP_TAIL(CA, CB, VM)                                                 \
    { __builtin_amdgcn_s_waitcnt(VM);                                          \
      __builtin_amdgcn_s_barrier();                                            \
      GFRAG_MFMA(CA, CB) }

#define GEMM_CORE(APTR, BPTR)                                                  \
  __shared__ __align__(16) unsigned short As0[128][32], As1[128][32],          \
      As2[128][32];                                                            \
  __shared__ __align__(16) unsigned short Bs0[128][32], Bs1[128][32],          \
      Bs2[128][32];                                                            \
  const int t = threadIdx.x;                                                   \
  const int w = t >> 6, lane = t & 63, quad = lane >> 4, l15 = lane & 15;      \
  const int moff = (w >> 1) * 64, noff = (w & 1) * 64;                         \
  const int m0 = blockIdx.y * 128, n0 = blockIdx.x * 128;                      \
  const int r_loc = lane >> 2, cphys = lane & 3;                               \
  const int r0 = w * 32 + r_loc, r1 = r0 + 16;                                 \
  const int sw = (r0 & 3) ^ ((r0 >> 2) & 1); /* same for r1 (=r0+16) */        \
  const int clog = (cphys ^ sw) * 8;                                           \
  const unsigned short* gA0 = (APTR) + (size_t)(m0 + r0) * E_ + clog;          \
  const unsigned short* gA1 = (APTR) + (size_t)(m0 + r1) * E_ + clog;          \
  const unsigned short* gB0 = (BPTR) + (size_t)(n0 + r0) * E_ + clog;          \
  const unsigned short* gB1 = (BPTR) + (size_t)(n0 + r1) * E_ + clog;          \
  const int sF = (l15 & 3) ^ ((l15 >> 2) & 1); /* frag-read swizzle */         \
  const int fcol = ((quad ^ sF)) * 8;                                          \
  floatx4 acc[4][4] = {};                                                      \
  GISSUE(As0, Bs0, 0)  /* tile 0 -> buf 0 */                                   \
  GISSUE(As1, Bs1, 1)  /* tile 1 -> buf 1 */                                   \
  for (int k3 = 0; k3 < 30; k3 += 3) {                                         \
    GSTEP(As0, Bs0, As2, Bs2, k3 + 2)                                          \
    GSTEP(As1, Bs1, As0, Bs0, k3 + 3)                                          \
    GSTEP(As2, Bs2, As1, Bs1, k3 + 4)                                          \
  }                                                                            \
  GSTEP_TAIL(As0, Bs0, 0x0F74) /* k=30: drains tile 30, tile 31 in flight */   \
  GSTEP_TAIL(As1, Bs1, 0x0F70) /* k=31: vmcnt(0) — last tile */

// ---------------------------------------------------------------------------
// Kernel 1: QKV projection GEMM. grid (24, 64). Epilogue: bias, Q pre-scaled
// by QSCALE, Q/K -> [B,H,S,D] bf16, V -> [B,H,D,S'] bf16 (transposed AND
// key-permuted within each 64-block: s' = (s&~63) | ((s&15)*4 + ((s>>4)&3)).
// PV is invariant under a shared key permutation of P and V; this makes the
// attention P-writes b64-packable while keeping V staging/reads contiguous).
// ---------------------------------------------------------------------------
__global__ __launch_bounds__(256) void gemm_qkv(
    const unsigned short* __restrict__ xb, const unsigned short* __restrict__ Wt,
    const float* __restrict__ bq, const float* __restrict__ bk,
    const float* __restrict__ bv,
    unsigned short* __restrict__ Q, unsigned short* __restrict__ K,
    unsigned short* __restrict__ V) {
  GEMM_CORE(xb, Wt)

  const int which = n0 >> 10;
  const float* bias = which == 0 ? bq : (which == 1 ? bk : bv);
  unsigned short* dst = which == 0 ? Q : (which == 1 ? K : V);
  const float sc = which == 0 ? QSCALE : 1.0f;
#pragma unroll
  for (int j = 0; j < 4; j++) {
    const int n = (n0 + noff + j * 16 + l15) & 1023;
    const int h = n >> 6, d = n & 63;
    const float bb = bias[n];
#pragma unroll
    for (int i = 0; i < 4; i++) {
#pragma unroll
      for (int r = 0; r < 4; r++) {
        const int m = m0 + moff + i * 16 + quad * 4 + r;
        const int b = m >> 11, s = m & 2047;
        const float val = (acc[i][j][r] + bb) * sc;
        if (which == 2) {  // V transposed + key-permuted: [B,H,D,S']
          const int sp = (s & ~63) | (((s & 15) << 2) | ((s >> 4) & 3));
          dst[(((size_t)(b * H_ + h) * D_) + d) * S_ + sp] = f2bf(val);
        } else {
          dst[(((size_t)(b * H_ + h) * S_) + s) * D_ + d] = f2bf(val);
        }
      }
    }
  }
}

// ---------------------------------------------------------------------------
// Kernel 2: flash attention, no-max softmax, exp2 domain, scale in Q.
// grid (16, 64). 4 waves x 32 q-rows. 64-key tiles, register-pipelined K/V
// staging. P stored in LDS at key' = (key&15)*4 + (key>>4): one b64 write per
// 4 C-values, pairs packed with v_perm round-half-up. V arrives already
// key'-permuted, so all fragment reads stay b128. Output AO[b][s][h*64+d].
// ---------------------------------------------------------------------------
__global__ __launch_bounds__(256, 4) void attn_kernel(
    const unsigned short* __restrict__ Q, const unsigned short* __restrict__ K,
    const unsigned short* __restrict__ Vt, unsigned short* __restrict__ AO) {
  __shared__ __align__(16) unsigned short Ks[64][72];   // [key][d]
  __shared__ __align__(16) unsigned short Vs[64][72];   // [d][key']
  __shared__ __align__(16) unsigned short Ps[128][72];  // [q][key']
  const int t = threadIdx.x;
  const int w = t >> 6, lane = t & 63, quad = lane >> 4, l15 = lane & 15;
  const int bh = blockIdx.y;
  const int q0 = blockIdx.x * 128;
  const int qb = w * 32;
  const size_t base = (size_t)bh * S_ * D_;

  bf16x8 qf[2][2];
#pragma unroll
  for (int mt = 0; mt < 2; mt++)
#pragma unroll
    for (int ks = 0; ks < 2; ks++)
      qf[mt][ks] = *(const bf16x8*)(Q + base +
                    (size_t)(q0 + qb + mt * 16 + l15) * D_ + ks * 32 + quad * 8);

  float l_i[2][4] = {};
  floatx4 O[2][4] = {};

  const int kk = t >> 2, cc = (t & 3) * 16;
  const unsigned short* kp = K  + base + (size_t)kk * D_ + cc;
  const unsigned short* vp = Vt + base + (size_t)kk * S_ + cc;

  uint4 kr0 = *(const uint4*)(kp);
  uint4 kr1 = *(const uint4*)(kp + 8);
  uint4 vr0 = *(const uint4*)(vp);
  uint4 vr1 = *(const uint4*)(vp + 8);

  for (int kt0 = 0; kt0 < S_; kt0 += 64) {
    *(uint4*)&Ks[kk][cc]     = kr0;
    *(uint4*)&Ks[kk][cc + 8] = kr1;
    *(uint4*)&Vs[kk][cc]     = vr0;
    *(uint4*)&Vs[kk][cc + 8] = vr1;
    __syncthreads();

    if (kt0 + 64 < S_) {  // prefetch next tile into registers
      kr0 = *(const uint4*)(kp + (size_t)(kt0 + 64) * D_);
      kr1 = *(const uint4*)(kp + (size_t)(kt0 + 64) * D_ + 8);
      vr0 = *(const uint4*)(vp + kt0 + 64);
      vr1 = *(const uint4*)(vp + kt0 + 72);
    }

    // S = Q K^T  (C-tile kt covers keys kt*16 + l15)
    floatx4 s[2][4] = {};
#pragma unroll
    for (int kt = 0; kt < 4; kt++) {
#pragma unroll
      for (int ks = 0; ks < 2; ks++) {
        bf16x8 kf = *(const bf16x8*)&Ks[kt * 16 + l15][ks * 32 + quad * 8];
#pragma unroll
        for (int mt = 0; mt < 2; mt++) s[mt][kt] = mfma16(qf[mt][ks], kf, s[mt][kt]);
      }
    }

    // p = exp2(s); key kt*16+l15 -> LDS col key' = l15*4+kt: the 4 kt-values
    // per (mt,r) are contiguous -> single b64 write of 2 packed u32.
#pragma unroll
    for (int mt = 0; mt < 2; mt++) {
#pragma unroll
      for (int r = 0; r < 4; r++) {
        const float p0 = __builtin_amdgcn_exp2f(s[mt][0][r]);
        const float p1 = __builtin_amdgcn_exp2f(s[mt][1][r]);
        const float p2 = __builtin_amdgcn_exp2f(s[mt][2][r]);
        const float p3 = __builtin_amdgcn_exp2f(s[mt][3][r]);
        l_i[mt][r] += (p0 + p1) + (p2 + p3);
        uint2 pk;
        pk.x = pack2bf(p0, p1);
        pk.y = pack2bf(p2, p3);
        *(uint2*)((char*)&Ps[qb + mt * 16 + quad * 4 + r][0] + l15 * 8) = pk;
      }
    }

    // O += P V   (both operands in key' order; Ps rows wave-private)
#pragma unroll
    for (int ks = 0; ks < 2; ks++) {
      bf16x8 pf[2];
#pragma unroll
      for (int mt = 0; mt < 2; mt++)
        pf[mt] = *(const bf16x8*)&Ps[qb + mt * 16 + l15][ks * 32 + quad * 8];
#pragma unroll
      for (int dt = 0; dt < 4; dt++) {
        bf16x8 vf = *(const bf16x8*)&Vs[dt * 16 + l15][ks * 32 + quad * 8];
#pragma unroll
        for (int mt = 0; mt < 2; mt++) O[mt][dt] = mfma16(pf[mt], vf, O[mt][dt]);
      }
    }
    __syncthreads();
  }

  const int b = bh >> 4, h = bh & 15;
#pragma unroll
  for (int mt = 0; mt < 2; mt++)
#pragma unroll
    for (int r = 0; r < 4; r++) {
      float sum = l_i[mt][r];
#pragma unroll
      for (int off = 1; off < 16; off <<= 1) sum += __shfl_xor(sum, off, 64);
      const float inv = 1.f / sum;
      const int srow = q0 + qb + mt * 16 + quad * 4 + r;
      unsigned short* aop = AO + (size_t)(b * S_ + srow) * E_ + h * D_ + l15;
#pragma unroll
      for (int dt = 0; dt < 4; dt++)
        aop[dt * 16] = f2bf(O[mt][dt][r] * inv);
    }
}

// ---------------------------------------------------------------------------
// Kernel 3: output projection GEMM. grid (8, 64). fp32 out + bias.
// ---------------------------------------------------------------------------
__global__ __launch_bounds__(256) void gemm_out(
    const unsigned short* __restrict__ A, const unsigned short* __restrict__ Wt,
    const float* __restrict__ bo, float* __restrict__ Cout) {
  GEMM_CORE(A, Wt)

#pragma unroll
  for (int j = 0; j < 4; j++) {
    const int n = n0 + noff + j * 16 + l15;
    const float bb = bo[n];
#pragma unroll
    for (int i = 0; i < 4; i++) {
#pragma unroll
      for (int r = 0; r < 4; r++) {
        const int m = m0 + moff + i * 16 + quad * 4 + r;
        Cout[(size_t)m * E_ + n] = acc[i][j][r] + bb;
      }
    }
  }
}

// ---------------------------------------------------------------------------
extern "C" void kernel_launch(void* const* d_in, const int* in_sizes, int n_in,
                              void* d_out, int out_size, void* d_ws, size_t ws_size,
                              hipStream_t stream) {
  const float* x  = (const float*)d_in[0];
  const float* Wq = (const float*)d_in[1];
  const float* bq = (const float*)d_in[2];
  const float* Wk = (const float*)d_in[3];
  const float* bk = (const float*)d_in[4];
  const float* Wv = (const float*)d_in[5];
  const float* bv = (const float*)d_in[6];
  const float* Wo = (const float*)d_in[7];
  const float* bo = (const float*)d_in[8];
  float* out = (float*)d_out;

  unsigned short* Wt = (unsigned short*)d_ws;
  unsigned short* Qb = Wt + (size_t)4 * E_ * E_;
  unsigned short* Kb = Qb + (size_t)B_ * H_ * S_ * D_;
  unsigned short* Vb = Kb + (size_t)B_ * H_ * S_ * D_;
  unsigned short* xb = Vb + (size_t)B_ * H_ * S_ * D_;
  unsigned short* AO = xb;  // alias: xb dead after gemm_qkv

  transpose4<<<dim3(32, 32, 4), dim3(32, 8), 0, stream>>>(Wq, Wk, Wv, Wo, Wt);
  cast_x<<<dim3(BS_ * E_ / (256 * 8)), 256, 0, stream>>>(x, xb);
  gemm_qkv<<<dim3(24, 64), 256, 0, stream>>>(xb, Wt, bq, bk, bv, Qb, Kb, Vb);
  attn_kernel<<<dim3(16, 64), 256, 0, stream>>>(Qb, Kb, Vb, AO);
  gemm_out<<<dim3(8, 64), 256, 0, stream>>>(AO, Wt + (size_t)3 * E_ * E_, bo, out);
}